// Round 14
// baseline (645.329 us; speedup 1.0000x reference)
//
#include <hip/hip_runtime.h>
#include <math.h>

#define NPTS 32768
#define NP   8192
#define KNN  16
#define CSPLIT 32
#define CHUNK (NP / CSPLIT)       // 256 candidates per scan chunk
#define SEGCAP 6                  // survivor slots per (query, chunk) segment
#define NSLOT (CSPLIT * SEGCAP)   // 192 slots per query
#define QPT 2                     // queries per thread in scan kernels
#define QBLK (256 * QPT)          // queries per scan block = 512

// Shared distance formula — byte-identical across all phases so float values
// match exactly (bound / filter / select consistency).
__device__ __forceinline__ float dist2f(float qx, float qy, float qz, float sqi, float4 t) {
    float dot = fmaf(qz, t.z, fmaf(qy, t.y, qx * t.x));
    return fmaf(-2.0f, dot, sqi) + t.w;   // reference formula ordering
}

// Branchless: maintain the 16 smallest VALUES seen (sorted ascending).
__device__ __forceinline__ void insert_val(float (&bd)[16], float d) {
    bd[15] = fminf(bd[15], d);
#pragma unroll
    for (int j = 15; j > 0; --j) {
        float lo = fminf(bd[j], bd[j - 1]);
        float hi = fmaxf(bd[j], bd[j - 1]);
        bd[j - 1] = lo; bd[j] = hi;
    }
}

// ---------------------------------------------------------------------------
// P1: bound, QPT=2, 32 chunks (grid 64x32 = 2048 blocks -> 32 waves/CU cap).
// Per (query, chunk): branchless 2-smallest; write BOTH, TRANSPOSED
// (pb2T[(chunk*2+s)*NPTS + q]) so stores are lane-coalesced.
// ---------------------------------------------------------------------------
__global__ __launch_bounds__(256) void knn_bound_kernel(
    const float4* __restrict__ coords, float* __restrict__ pb2T)
{
    __shared__ float4 tile[CHUNK];   // 4 KB

    const int tid = threadIdx.x;
    const int qb  = blockIdx.x * QBLK;          // 512-query window, no batch straddle
    const int batch = qb / NP;
    const int cbase = batch * NP + blockIdx.y * CHUNK;

    {   // one candidate per thread (CHUNK == blockDim)
        float4 f = coords[cbase + tid];                 // [bidx, x, y, z]
        float sq = fmaf(f.w, f.w, fmaf(f.z, f.z, f.y * f.y));
        tile[tid] = make_float4(f.y, f.z, f.w, sq);
    }

    const int q0 = qb + tid, q1 = qb + 256 + tid;
    float4 qf0 = coords[q0];
    float4 qf1 = coords[q1];
    const float qx0 = qf0.y, qy0 = qf0.z, qz0 = qf0.w;
    const float qx1 = qf1.y, qy1 = qf1.z, qz1 = qf1.w;
    const float sqi0 = fmaf(qz0, qz0, fmaf(qy0, qy0, qx0 * qx0));
    const float sqi1 = fmaf(qz1, qz1, fmaf(qy1, qy1, qx1 * qx1));

    float a0 = INFINITY, a1 = INFINITY;   // q0: smallest, 2nd-smallest
    float b0 = INFINITY, b1 = INFINITY;   // q1
    __syncthreads();

#pragma unroll 4
    for (int c = 0; c < CHUNK; ++c) {
        float4 t = tile[c];
        float d0 = dist2f(qx0, qy0, qz0, sqi0, t);
        float d1 = dist2f(qx1, qy1, qz1, sqi1, t);
        float t0 = fminf(a1, d0);
        a1 = fmaxf(a0, t0);
        a0 = fminf(a0, t0);
        float t1 = fminf(b1, d1);
        b1 = fmaxf(b0, t1);
        b0 = fminf(b0, t1);
    }
    const size_t r0 = (size_t)(blockIdx.y * 2) * NPTS;
    const size_t r1 = r0 + NPTS;
    pb2T[r0 + q0] = a0; pb2T[r1 + q0] = a1;   // coalesced
    pb2T[r0 + q1] = b0; pb2T[r1 + q1] = b1;
}

// ---------------------------------------------------------------------------
// P1.5: tau_q = 16th smallest of the 64 per-chunk top-2 values. The 16
// values <= tau belong to 16 DISTINCT candidates (top-2 of disjoint chunks)
// => tau >= d16 exactly. Transposed reads are lane-coalesced.
// ---------------------------------------------------------------------------
__global__ __launch_bounds__(256) void tau_init_kernel(
    const float* __restrict__ pb2T, float* __restrict__ tau)
{
    const int q = blockIdx.x * 256 + threadIdx.x;

    float bd[16];
#pragma unroll
    for (int j = 0; j < 16; ++j) bd[j] = INFINITY;
#pragma unroll
    for (int v = 0; v < 2 * CSPLIT; ++v)
        insert_val(bd, pb2T[(size_t)v * NPTS + q]);
    tau[q] = bd[15];
}

// ---------------------------------------------------------------------------
// P2: filter, QPT=2, ATOMIC-FREE, 32 segments/query. One thread scans each
// (query, chunk) => thread-local counter, fire-and-forget stores. Accept
// path branchless slot clamp; raw count written at end (overflow detect).
// ---------------------------------------------------------------------------
__global__ __launch_bounds__(256) void knn_filter_kernel(
    const float4* __restrict__ coords, const float* __restrict__ tau,
    int* __restrict__ pc, int* __restrict__ surv)
{
    __shared__ float4 tile[CHUNK];

    const int tid = threadIdx.x;
    const int qb  = blockIdx.x * QBLK;
    const int batch = qb / NP;
    const int cbase = batch * NP + blockIdx.y * CHUNK;

    {
        float4 f = coords[cbase + tid];
        float sq = fmaf(f.w, f.w, fmaf(f.z, f.z, f.y * f.y));
        tile[tid] = make_float4(f.y, f.z, f.w, sq);
    }

    const int q0 = qb + tid, q1 = qb + 256 + tid;
    float4 qf0 = coords[q0];
    float4 qf1 = coords[q1];
    const float qx0 = qf0.y, qy0 = qf0.z, qz0 = qf0.w;
    const float qx1 = qf1.y, qy1 = qf1.z, qz1 = qf1.w;
    const float sqi0 = fmaf(qz0, qz0, fmaf(qy0, qy0, qx0 * qx0));
    const float sqi1 = fmaf(qz1, qz1, fmaf(qy1, qy1, qx1 * qx1));
    const float tq0 = tau[q0], tq1 = tau[q1];

    const size_t sb0 = (size_t)q0 * NSLOT + blockIdx.y * SEGCAP;
    const size_t sb1 = (size_t)q1 * NSLOT + blockIdx.y * SEGCAP;
    int cnt0 = 0, cnt1 = 0;
    __syncthreads();

#pragma unroll 4
    for (int c = 0; c < CHUNK; ++c) {
        float4 t = tile[c];
        float d0 = dist2f(qx0, qy0, qz0, sqi0, t);
        float d1 = dist2f(qx1, qy1, qz1, sqi1, t);
        if (d0 <= tq0) {
            surv[sb0 + (cnt0 < SEGCAP ? cnt0 : SEGCAP - 1)] = cbase + c;
            ++cnt0;
        }
        if (d1 <= tq1) {
            surv[sb1 + (cnt1 < SEGCAP ? cnt1 : SEGCAP - 1)] = cbase + c;
            ++cnt1;
        }
    }
    pc[q0 * CSPLIT + blockIdx.y] = cnt0;
    pc[q1 * CSPLIT + blockIdx.y] = cnt1;
}

// ---------------------------------------------------------------------------
// P3: WAVE-PARALLEL exact top-16 + layer-1 a1/c1, compacted rank.
// One wave per query. Survivors compacted into LDS via prefix offsets. Rank
// loop runs k < n (~30 avg). Lex (d,id) strict total order -> bijective
// ranks, exact jax tie-break. Segment overflow (~0.06% of queries) ->
// WAVE-PARALLEL 16-round extraction. Single-wave block => uniform-control
// __syncthreads only.
// ---------------------------------------------------------------------------
__global__ __launch_bounds__(64) void knn_select_ac1_kernel(
    const float4* __restrict__ coords, const int* __restrict__ pc,
    const int* __restrict__ surv,
    const float* __restrict__ feat, const float* __restrict__ W1,
    const float* __restrict__ b1,
    int* __restrict__ knn, float* __restrict__ a1, float* __restrict__ c1)
{
    __shared__ float sd[NSLOT];
    __shared__ int   si[NSLOT];
    __shared__ int   spc[CSPLIT];
    __shared__ int   soff[CSPLIT];
    __shared__ int   outi[16];
    __shared__ float sx[16];

    const int lane = threadIdx.x;
    const int q    = blockIdx.x;

    float4 qf = coords[q];
    const float qx = qf.y, qy = qf.z, qz = qf.w;
    const float sqi = fmaf(qz, qz, fmaf(qy, qy, qx * qx));

    if (lane < CSPLIT) spc[lane] = pc[q * CSPLIT + lane];
    __syncthreads();

    // Wave-uniform scalars: overflow flag + total n; prefix offsets -> LDS.
    bool over = false;
    int acc = 0;
#pragma unroll
    for (int s = 0; s < CSPLIT; ++s) {
        int c = spc[s];
        over |= (c > SEGCAP);
        if (lane == 0) soff[s] = acc;
        acc += c;
    }
    const int n = acc;                        // >= 16 by construction when !over
    __syncthreads();

    if (!over) {
        // Compacted stage: slot j -> LDS position soff[seg]+o (injective).
#pragma unroll
        for (int b = 0; b < 3; ++b) {
            const int j = b * 64 + lane;      // j < 192
            const int seg = j / SEGCAP;
            const int o   = j - seg * SEGCAP;
            if (o < spc[seg]) {
                int id = surv[(size_t)q * NSLOT + j];
                float4 f = coords[id];
                float sq = fmaf(f.w, f.w, fmaf(f.z, f.z, f.y * f.y));
                float d = dist2f(qx, qy, qz, sqi, make_float4(f.y, f.z, f.w, sq));
                const int pos = soff[seg] + o;
                sd[pos] = d; si[pos] = id;
            }
        }
        __syncthreads();

        if (n <= 64) {                        // dominant path (n ~ 25-40)
            float dm = INFINITY; int im = 0x7fffffff;
            if (lane < n) { dm = sd[lane]; im = si[lane]; }
            int r = 0;
            for (int k = 0; k < n; ++k) {     // LDS broadcast reads
                float dk = sd[k]; int ik = si[k];
                r += ((dk < dm) || (dk == dm && ik < im)) ? 1 : 0;
            }
            if (lane < n && r < 16) outi[r] = im;
        } else {
            float dm[3]; int im[3];
#pragma unroll
            for (int b = 0; b < 3; ++b) {
                const int m = b * 64 + lane;
                dm[b] = (m < n) ? sd[m] : INFINITY;
                im[b] = (m < n) ? si[m] : 0x7fffffff;
            }
            int r0 = 0, r1 = 0, r2 = 0;
            for (int k = 0; k < n; ++k) {
                float dk = sd[k]; int ik = si[k];
                r0 += ((dk < dm[0]) || (dk == dm[0] && ik < im[0])) ? 1 : 0;
                r1 += ((dk < dm[1]) || (dk == dm[1] && ik < im[1])) ? 1 : 0;
                r2 += ((dk < dm[2]) || (dk == dm[2] && ik < im[2])) ? 1 : 0;
            }
            if (lane       < n && r0 < 16) outi[r0] = im[0];
            if (lane + 64  < n && r1 < 16) outi[r1] = im[1];
            if (lane + 128 < n && r2 < 16) outi[r2] = im[2];
        }
        __syncthreads();
    } else {
        // WAVE-PARALLEL exact fallback: 16 extraction rounds over the batch.
        const int b0 = (q / NP) * NP;
        float lastd = -INFINITY; int lasti = -1;
        for (int r = 0; r < 16; ++r) {
            float md = INFINITY; int mi = 0x7fffffff;
            for (int c = lane; c < NP; c += 64) {
                int id = b0 + c;
                float4 f = coords[id];
                float sq = fmaf(f.w, f.w, fmaf(f.z, f.z, f.y * f.y));
                float d = dist2f(qx, qy, qz, sqi, make_float4(f.y, f.z, f.w, sq));
                bool gt_last = (d > lastd) || (d == lastd && id > lasti);
                bool lt_min  = (d < md) || (d == md && id < mi);
                if (gt_last && lt_min) { md = d; mi = id; }
            }
#pragma unroll
            for (int s = 1; s < 64; s <<= 1) {     // lex-min butterfly
                float od = __shfl_xor(md, s);
                int   oi = __shfl_xor(mi, s);
                bool less = (od < md) || (od == md && oi < mi);
                md = less ? od : md;
                mi = less ? oi : mi;
            }
            if (lane == 0) outi[r] = mi;
            lastd = md; lasti = mi;                // uniform after butterfly
        }
        __syncthreads();
    }

    if (lane < 16) {
        knn[q * 16 + lane] = outi[lane];
        sx[lane] = feat[(size_t)q * 16 + lane];
    }
    __syncthreads();

    // ---- a1/c1: lane c (<16) computes channel c ----
    if (lane < 16) {
        float av = b1[lane], cv = 0.0f;
#pragma unroll
        for (int r = 0; r < 16; ++r) {
            float xr = sx[r];
            float wt = W1[r * 16 + lane];
            float wb = W1[(16 + r) * 16 + lane];
            av = fmaf(xr, wt - wb, av);
            cv = fmaf(xr, wb, cv);
        }
        a1[(size_t)q * 16 + lane] = av;
        c1[(size_t)q * 16 + lane] = cv;
    }
}

// ---------------------------------------------------------------------------
// EdgeConv (unchanged, passing since round 0):
//   x_out[i] = relu( max_k (a[i] + c[knn[i][k]]) )
// ---------------------------------------------------------------------------
template<int COUT, int CNXT, bool LAST>
__global__ __launch_bounds__(256) void edgeconv_kernel(
    const float* __restrict__ a, const float* __restrict__ cf,
    const int* __restrict__ knn,
    const float* __restrict__ Wn, const float* __restrict__ bn,
    float* __restrict__ an, float* __restrict__ cn, float* __restrict__ out)
{
    constexpr int CPG  = COUT / 4;
    constexpr int CPGN = LAST ? 4 : CNXT / 4;
    constexpr int WSZ  = LAST ? 1 : COUT * CNXT;

    __shared__ float xs[64][COUT + 1];
    __shared__ __align__(16) float wm[WSZ];
    __shared__ __align__(16) float wb[WSZ];

    const int tid = threadIdx.x;
    const int g = tid & 3, p = tid >> 2;
    const int i = blockIdx.x * 64 + p;

    if constexpr (!LAST) {
        for (int t = tid; t < COUT * CNXT; t += 256) {
            float top = Wn[t], bot = Wn[COUT * CNXT + t];
            wm[t] = top - bot; wb[t] = bot;
        }
    }

    float av[CPG], m[CPG];
    const float4* a4 = (const float4*)(a + (size_t)i * COUT + g * CPG);
#pragma unroll
    for (int v = 0; v < CPG / 4; ++v) {
        float4 f = a4[v];
        av[4*v] = f.x; av[4*v+1] = f.y; av[4*v+2] = f.z; av[4*v+3] = f.w;
    }
#pragma unroll
    for (int c = 0; c < CPG; ++c) m[c] = -INFINITY;

    const int4* kn = (const int4*)(knn + (size_t)i * 16);
#pragma unroll
    for (int kk = 0; kk < 4; ++kk) {
        int4 n4 = kn[kk];
        int js[4] = { n4.x, n4.y, n4.z, n4.w };
#pragma unroll
        for (int u = 0; u < 4; ++u) {
            const float4* c4 = (const float4*)(cf + (size_t)js[u] * COUT + g * CPG);
#pragma unroll
            for (int v = 0; v < CPG / 4; ++v) {
                float4 f = c4[v];
                m[4*v+0] = fmaxf(m[4*v+0], av[4*v+0] + f.x);
                m[4*v+1] = fmaxf(m[4*v+1], av[4*v+1] + f.y);
                m[4*v+2] = fmaxf(m[4*v+2], av[4*v+2] + f.z);
                m[4*v+3] = fmaxf(m[4*v+3], av[4*v+3] + f.w);
            }
        }
    }
    float xv[CPG];
#pragma unroll
    for (int c = 0; c < CPG; ++c) xv[c] = fmaxf(m[c], 0.0f);

    if constexpr (LAST) {
        float4* o4 = (float4*)(out + (size_t)i * COUT + g * CPG);
#pragma unroll
        for (int v = 0; v < CPG / 4; ++v)
            o4[v] = make_float4(xv[4*v], xv[4*v+1], xv[4*v+2], xv[4*v+3]);
    } else {
#pragma unroll
        for (int c = 0; c < CPG; ++c) xs[p][g * CPG + c] = xv[c];
        __syncthreads();

        float aacc[CPGN], cacc[CPGN];
        const float4* bn4 = (const float4*)(bn + g * CPGN);
#pragma unroll
        for (int v = 0; v < CPGN / 4; ++v) {
            float4 f = bn4[v];
            aacc[4*v] = f.x; aacc[4*v+1] = f.y; aacc[4*v+2] = f.z; aacc[4*v+3] = f.w;
        }
#pragma unroll
        for (int c = 0; c < CPGN; ++c) cacc[c] = 0.0f;

#pragma unroll
        for (int r = 0; r < COUT; ++r) {
            float xr = xs[p][r];
            const float4* wm4 = (const float4*)(wm + r * CNXT + g * CPGN);
            const float4* wb4 = (const float4*)(wb + r * CNXT + g * CPGN);
#pragma unroll
            for (int v = 0; v < CPGN / 4; ++v) {
                float4 fm = wm4[v], fb = wb4[v];
                aacc[4*v+0] = fmaf(xr, fm.x, aacc[4*v+0]);
                aacc[4*v+1] = fmaf(xr, fm.y, aacc[4*v+1]);
                aacc[4*v+2] = fmaf(xr, fm.z, aacc[4*v+2]);
                aacc[4*v+3] = fmaf(xr, fm.w, aacc[4*v+3]);
                cacc[4*v+0] = fmaf(xr, fb.x, cacc[4*v+0]);
                cacc[4*v+1] = fmaf(xr, fb.y, cacc[4*v+1]);
                cacc[4*v+2] = fmaf(xr, fb.z, cacc[4*v+2]);
                cacc[4*v+3] = fmaf(xr, fb.w, cacc[4*v+3]);
            }
        }
        float4* an4 = (float4*)(an + (size_t)i * CNXT + g * CPGN);
        float4* cn4 = (float4*)(cn + (size_t)i * CNXT + g * CPGN);
#pragma unroll
        for (int v = 0; v < CPGN / 4; ++v) {
            an4[v] = make_float4(aacc[4*v], aacc[4*v+1], aacc[4*v+2], aacc[4*v+3]);
            cn4[v] = make_float4(cacc[4*v], cacc[4*v+1], cacc[4*v+2], cacc[4*v+3]);
        }
    }
}

// ---------------------------------------------------------------------------
// Workspace layout (bytes), peak 34.2 MB (< 37 proven):
//   [0,24M)   : surv (32768 x 192 int, segmented 32x6)  -- dead after P3
//   [24M,32M) : pb2T (64 x 32768 float, transposed)     -- dead after tau
//     reuse (post-tau): knn [24,26) ; a1 [26,28) ; c1 [28,30)
//   [30M,34M) : pc  (32768 x 32 int)
//   [34M,+128K): tau
//   reuse (post-select): a2=[0,4M) c2=[4,8M) a3=[8,12M) c3=[12,16M)
// ---------------------------------------------------------------------------
extern "C" void kernel_launch(void* const* d_in, const int* in_sizes, int n_in,
                              void* d_out, int out_size, void* d_ws, size_t ws_size,
                              hipStream_t stream) {
    const float4* coords = (const float4*)d_in[0];
    const float*  feat   = (const float*)d_in[1];
    const float*  W1 = (const float*)d_in[2];
    const float*  b1 = (const float*)d_in[3];
    const float*  W2 = (const float*)d_in[4];
    const float*  b2 = (const float*)d_in[5];
    const float*  W3 = (const float*)d_in[6];
    const float*  b3 = (const float*)d_in[7];
    float* out = (float*)d_out;

    char* ws = (char*)d_ws;
    int*   surv = (int*)  (ws);
    float* pb2T = (float*)(ws + (24u << 20));
    int*   knn  = (int*)  (ws + (24u << 20));   // overlaps pb2T (dead after tau)
    float* a1   = (float*)(ws + (26u << 20));
    float* c1   = (float*)(ws + (28u << 20));
    int*   pc   = (int*)  (ws + (30u << 20));
    float* tau  = (float*)(ws + (34u << 20));
    float* a2   = (float*)(ws + (0u  << 20));
    float* c2   = (float*)(ws + (4u  << 20));
    float* a3   = (float*)(ws + (8u  << 20));
    float* c3   = (float*)(ws + (12u << 20));

    knn_bound_kernel<<<dim3(NPTS / QBLK, CSPLIT), 256, 0, stream>>>(coords, pb2T);
    tau_init_kernel<<<NPTS / 256, 256, 0, stream>>>(pb2T, tau);
    knn_filter_kernel<<<dim3(NPTS / QBLK, CSPLIT), 256, 0, stream>>>(coords, tau, pc, surv);
    knn_select_ac1_kernel<<<NPTS, 64, 0, stream>>>(coords, pc, surv, feat, W1, b1, knn, a1, c1);
    edgeconv_kernel<16, 32, false><<<NPTS / 64, 256, 0, stream>>>(a1, c1, knn, W2, b2, a2, c2, nullptr);
    edgeconv_kernel<32, 32, false><<<NPTS / 64, 256, 0, stream>>>(a2, c2, knn, W3, b3, a3, c3, nullptr);
    edgeconv_kernel<32, 4, true><<<NPTS / 64, 256, 0, stream>>>(a3, c3, knn, nullptr, nullptr, nullptr, nullptr, out);
}

// Round 15
// 639.228 us; speedup vs baseline: 1.0095x; 1.0095x over previous
//
#include <hip/hip_runtime.h>
#include <math.h>

#define NPTS 32768
#define NP   8192
#define KNN  16
#define CSPLIT 32
#define CHUNK (NP / CSPLIT)       // 256 candidates per scan chunk
#define SEGCAP 6                  // survivor slots per (query, chunk) segment
#define NSLOT (CSPLIT * SEGCAP)   // 192 slots per query
#define QPT 2                     // queries per thread in scan kernels
#define QBLK (256 * QPT)          // queries per scan block = 512
#define SELQ 4                    // queries per select block (1 wave each)

// Shared distance formula — byte-identical across all phases so float values
// match exactly (bound / filter / select consistency).
__device__ __forceinline__ float dist2f(float qx, float qy, float qz, float sqi, float4 t) {
    float dot = fmaf(qz, t.z, fmaf(qy, t.y, qx * t.x));
    return fmaf(-2.0f, dot, sqi) + t.w;   // reference formula ordering
}

// Branchless: maintain the 16 smallest VALUES seen (sorted ascending).
__device__ __forceinline__ void insert_val(float (&bd)[16], float d) {
    bd[15] = fminf(bd[15], d);
#pragma unroll
    for (int j = 15; j > 0; --j) {
        float lo = fminf(bd[j], bd[j - 1]);
        float hi = fmaxf(bd[j], bd[j - 1]);
        bd[j - 1] = lo; bd[j] = hi;
    }
}

// ---------------------------------------------------------------------------
// P1: bound, QPT=2, 32 chunks (grid 64x32 = 2048 blocks -> 32 waves/CU cap).
// Per (query, chunk): branchless 2-smallest; write BOTH, TRANSPOSED
// (pb2T[(chunk*2+s)*NPTS + q]) so stores are lane-coalesced.
// ---------------------------------------------------------------------------
__global__ __launch_bounds__(256) void knn_bound_kernel(
    const float4* __restrict__ coords, float* __restrict__ pb2T)
{
    __shared__ float4 tile[CHUNK];   // 4 KB

    const int tid = threadIdx.x;
    const int qb  = blockIdx.x * QBLK;          // 512-query window, no batch straddle
    const int batch = qb / NP;
    const int cbase = batch * NP + blockIdx.y * CHUNK;

    {   // one candidate per thread (CHUNK == blockDim)
        float4 f = coords[cbase + tid];                 // [bidx, x, y, z]
        float sq = fmaf(f.w, f.w, fmaf(f.z, f.z, f.y * f.y));
        tile[tid] = make_float4(f.y, f.z, f.w, sq);
    }

    const int q0 = qb + tid, q1 = qb + 256 + tid;
    float4 qf0 = coords[q0];
    float4 qf1 = coords[q1];
    const float qx0 = qf0.y, qy0 = qf0.z, qz0 = qf0.w;
    const float qx1 = qf1.y, qy1 = qf1.z, qz1 = qf1.w;
    const float sqi0 = fmaf(qz0, qz0, fmaf(qy0, qy0, qx0 * qx0));
    const float sqi1 = fmaf(qz1, qz1, fmaf(qy1, qy1, qx1 * qx1));

    float a0 = INFINITY, a1 = INFINITY;   // q0: smallest, 2nd-smallest
    float b0 = INFINITY, b1 = INFINITY;   // q1
    __syncthreads();

#pragma unroll 4
    for (int c = 0; c < CHUNK; ++c) {
        float4 t = tile[c];
        float d0 = dist2f(qx0, qy0, qz0, sqi0, t);
        float d1 = dist2f(qx1, qy1, qz1, sqi1, t);
        float t0 = fminf(a1, d0);
        a1 = fmaxf(a0, t0);
        a0 = fminf(a0, t0);
        float t1 = fminf(b1, d1);
        b1 = fmaxf(b0, t1);
        b0 = fminf(b0, t1);
    }
    const size_t r0 = (size_t)(blockIdx.y * 2) * NPTS;
    const size_t r1 = r0 + NPTS;
    pb2T[r0 + q0] = a0; pb2T[r1 + q0] = a1;   // coalesced
    pb2T[r0 + q1] = b0; pb2T[r1 + q1] = b1;
}

// ---------------------------------------------------------------------------
// P1.5: tau_q = 16th smallest of the 64 per-chunk top-2 values. The 16
// values <= tau belong to 16 DISTINCT candidates (top-2 of disjoint chunks)
// => tau >= d16 exactly. Transposed reads are lane-coalesced.
// ---------------------------------------------------------------------------
__global__ __launch_bounds__(256) void tau_init_kernel(
    const float* __restrict__ pb2T, float* __restrict__ tau)
{
    const int q = blockIdx.x * 256 + threadIdx.x;

    float bd[16];
#pragma unroll
    for (int j = 0; j < 16; ++j) bd[j] = INFINITY;
#pragma unroll
    for (int v = 0; v < 2 * CSPLIT; ++v)
        insert_val(bd, pb2T[(size_t)v * NPTS + q]);
    tau[q] = bd[15];
}

// ---------------------------------------------------------------------------
// P2: filter, QPT=2, ATOMIC-FREE, 32 segments/query. One thread scans each
// (query, chunk) => thread-local counter, fire-and-forget stores. Accept
// path branchless slot clamp; raw count written at end (overflow detect).
// ---------------------------------------------------------------------------
__global__ __launch_bounds__(256) void knn_filter_kernel(
    const float4* __restrict__ coords, const float* __restrict__ tau,
    int* __restrict__ pc, int* __restrict__ surv)
{
    __shared__ float4 tile[CHUNK];

    const int tid = threadIdx.x;
    const int qb  = blockIdx.x * QBLK;
    const int batch = qb / NP;
    const int cbase = batch * NP + blockIdx.y * CHUNK;

    {
        float4 f = coords[cbase + tid];
        float sq = fmaf(f.w, f.w, fmaf(f.z, f.z, f.y * f.y));
        tile[tid] = make_float4(f.y, f.z, f.w, sq);
    }

    const int q0 = qb + tid, q1 = qb + 256 + tid;
    float4 qf0 = coords[q0];
    float4 qf1 = coords[q1];
    const float qx0 = qf0.y, qy0 = qf0.z, qz0 = qf0.w;
    const float qx1 = qf1.y, qy1 = qf1.z, qz1 = qf1.w;
    const float sqi0 = fmaf(qz0, qz0, fmaf(qy0, qy0, qx0 * qx0));
    const float sqi1 = fmaf(qz1, qz1, fmaf(qy1, qy1, qx1 * qx1));
    const float tq0 = tau[q0], tq1 = tau[q1];

    const size_t sb0 = (size_t)q0 * NSLOT + blockIdx.y * SEGCAP;
    const size_t sb1 = (size_t)q1 * NSLOT + blockIdx.y * SEGCAP;
    int cnt0 = 0, cnt1 = 0;
    __syncthreads();

#pragma unroll 4
    for (int c = 0; c < CHUNK; ++c) {
        float4 t = tile[c];
        float d0 = dist2f(qx0, qy0, qz0, sqi0, t);
        float d1 = dist2f(qx1, qy1, qz1, sqi1, t);
        if (d0 <= tq0) {
            surv[sb0 + (cnt0 < SEGCAP ? cnt0 : SEGCAP - 1)] = cbase + c;
            ++cnt0;
        }
        if (d1 <= tq1) {
            surv[sb1 + (cnt1 < SEGCAP ? cnt1 : SEGCAP - 1)] = cbase + c;
            ++cnt1;
        }
    }
    pc[q0 * CSPLIT + blockIdx.y] = cnt0;
    pc[q1 * CSPLIT + blockIdx.y] = cnt1;
}

// ---------------------------------------------------------------------------
// P3: WAVE-PARALLEL exact top-16 + layer-1 a1/c1, compacted rank.
// RESTRUCTURED vs round 14: 4 queries per 256-thread block (8192 blocks),
// one WAVE per query with a private LDS slice, and ZERO barriers — every
// LDS dependency is within a single wave, ordered by the compiler's lgkmcnt
// tracking. This removes the 32768-tiny-block shape that showed a 20x
// concurrency collapse (occ 5.6%, VALUBusy 4.4%) in round 14, and has no
// divergent-barrier hazard (no barriers at all). Rank logic unchanged:
// lex (d,id) strict total order -> bijective ranks, exact jax tie-break.
// Segment overflow -> per-wave shuffle-only exact extraction.
// ---------------------------------------------------------------------------
__global__ __launch_bounds__(256) void knn_select_ac1_kernel(
    const float4* __restrict__ coords, const int* __restrict__ pc,
    const int* __restrict__ surv,
    const float* __restrict__ feat, const float* __restrict__ W1,
    const float* __restrict__ b1,
    int* __restrict__ knn, float* __restrict__ a1, float* __restrict__ c1)
{
    __shared__ float sd[SELQ][NSLOT];
    __shared__ int   si[SELQ][NSLOT];
    __shared__ int   spc[SELQ][CSPLIT];
    __shared__ int   soff[SELQ][CSPLIT];
    __shared__ int   outi[SELQ][16];
    __shared__ float sx[SELQ][16];

    const int lane = threadIdx.x & 63;
    const int w    = threadIdx.x >> 6;          // wave id = query slot
    const int q    = blockIdx.x * SELQ + w;

    float4 qf = coords[q];
    const float qx = qf.y, qy = qf.z, qz = qf.w;
    const float sqi = fmaf(qz, qz, fmaf(qy, qy, qx * qx));

    if (lane < CSPLIT) spc[w][lane] = pc[q * CSPLIT + lane];
    // same-wave LDS dep: no barrier needed

    // Wave-uniform scalars: overflow flag + total n; prefix offsets -> LDS.
    bool over = false;
    int acc = 0;
#pragma unroll
    for (int s = 0; s < CSPLIT; ++s) {
        int c = spc[w][s];
        over |= (c > SEGCAP);
        if (lane == 0) soff[w][s] = acc;
        acc += c;
    }
    const int n = acc;                        // >= 16 by construction when !over

    if (!over) {
        // Compacted stage: slot j -> LDS position soff[seg]+o (injective).
#pragma unroll
        for (int b = 0; b < 3; ++b) {
            const int j = b * 64 + lane;      // j < 192
            const int seg = j / SEGCAP;
            const int o   = j - seg * SEGCAP;
            if (o < spc[w][seg]) {
                int id = surv[(size_t)q * NSLOT + j];
                float4 f = coords[id];
                float sq = fmaf(f.w, f.w, fmaf(f.z, f.z, f.y * f.y));
                float d = dist2f(qx, qy, qz, sqi, make_float4(f.y, f.z, f.w, sq));
                const int pos = soff[w][seg] + o;
                sd[w][pos] = d; si[w][pos] = id;
            }
        }

        if (n <= 64) {                        // dominant path (n ~ 16-30)
            float dm = INFINITY; int im = 0x7fffffff;
            if (lane < n) { dm = sd[w][lane]; im = si[w][lane]; }
            int r = 0;
            for (int k = 0; k < n; ++k) {     // LDS broadcast reads
                float dk = sd[w][k]; int ik = si[w][k];
                r += ((dk < dm) || (dk == dm && ik < im)) ? 1 : 0;
            }
            if (lane < n && r < 16) outi[w][r] = im;
        } else {
            float dm[3]; int im[3];
#pragma unroll
            for (int b = 0; b < 3; ++b) {
                const int m = b * 64 + lane;
                dm[b] = (m < n) ? sd[w][m] : INFINITY;
                im[b] = (m < n) ? si[w][m] : 0x7fffffff;
            }
            int r0 = 0, r1 = 0, r2 = 0;
            for (int k = 0; k < n; ++k) {
                float dk = sd[w][k]; int ik = si[w][k];
                r0 += ((dk < dm[0]) || (dk == dm[0] && ik < im[0])) ? 1 : 0;
                r1 += ((dk < dm[1]) || (dk == dm[1] && ik < im[1])) ? 1 : 0;
                r2 += ((dk < dm[2]) || (dk == dm[2] && ik < im[2])) ? 1 : 0;
            }
            if (lane       < n && r0 < 16) outi[w][r0] = im[0];
            if (lane + 64  < n && r1 < 16) outi[w][r1] = im[1];
            if (lane + 128 < n && r2 < 16) outi[w][r2] = im[2];
        }
    } else {
        // WAVE-PARALLEL exact fallback: 16 extraction rounds over the batch.
        // Shuffle-only (no shared LDS, no barriers) -> safe per-wave.
        const int b0 = (q / NP) * NP;
        float lastd = -INFINITY; int lasti = -1;
        for (int r = 0; r < 16; ++r) {
            float md = INFINITY; int mi = 0x7fffffff;
            for (int c = lane; c < NP; c += 64) {
                int id = b0 + c;
                float4 f = coords[id];
                float sq = fmaf(f.w, f.w, fmaf(f.z, f.z, f.y * f.y));
                float d = dist2f(qx, qy, qz, sqi, make_float4(f.y, f.z, f.w, sq));
                bool gt_last = (d > lastd) || (d == lastd && id > lasti);
                bool lt_min  = (d < md) || (d == md && id < mi);
                if (gt_last && lt_min) { md = d; mi = id; }
            }
#pragma unroll
            for (int s = 1; s < 64; s <<= 1) {     // lex-min butterfly
                float od = __shfl_xor(md, s);
                int   oi = __shfl_xor(mi, s);
                bool less = (od < md) || (od == md && oi < mi);
                md = less ? od : md;
                mi = less ? oi : mi;
            }
            if (lane == 0) outi[w][r] = mi;
            lastd = md; lasti = mi;                // uniform after butterfly
        }
    }

    if (lane < 16) {
        knn[q * 16 + lane] = outi[w][lane];
        sx[w][lane] = feat[(size_t)q * 16 + lane];
    }
    // same-wave LDS dep: no barrier needed

    // ---- a1/c1: lane c (<16) computes channel c ----
    if (lane < 16) {
        float av = b1[lane], cv = 0.0f;
#pragma unroll
        for (int r = 0; r < 16; ++r) {
            float xr = sx[w][r];
            float wt = W1[r * 16 + lane];
            float wb = W1[(16 + r) * 16 + lane];
            av = fmaf(xr, wt - wb, av);
            cv = fmaf(xr, wb, cv);
        }
        a1[(size_t)q * 16 + lane] = av;
        c1[(size_t)q * 16 + lane] = cv;
    }
}

// ---------------------------------------------------------------------------
// EdgeConv (unchanged, passing since round 0):
//   x_out[i] = relu( max_k (a[i] + c[knn[i][k]]) )
// ---------------------------------------------------------------------------
template<int COUT, int CNXT, bool LAST>
__global__ __launch_bounds__(256) void edgeconv_kernel(
    const float* __restrict__ a, const float* __restrict__ cf,
    const int* __restrict__ knn,
    const float* __restrict__ Wn, const float* __restrict__ bn,
    float* __restrict__ an, float* __restrict__ cn, float* __restrict__ out)
{
    constexpr int CPG  = COUT / 4;
    constexpr int CPGN = LAST ? 4 : CNXT / 4;
    constexpr int WSZ  = LAST ? 1 : COUT * CNXT;

    __shared__ float xs[64][COUT + 1];
    __shared__ __align__(16) float wm[WSZ];
    __shared__ __align__(16) float wb[WSZ];

    const int tid = threadIdx.x;
    const int g = tid & 3, p = tid >> 2;
    const int i = blockIdx.x * 64 + p;

    if constexpr (!LAST) {
        for (int t = tid; t < COUT * CNXT; t += 256) {
            float top = Wn[t], bot = Wn[COUT * CNXT + t];
            wm[t] = top - bot; wb[t] = bot;
        }
    }

    float av[CPG], m[CPG];
    const float4* a4 = (const float4*)(a + (size_t)i * COUT + g * CPG);
#pragma unroll
    for (int v = 0; v < CPG / 4; ++v) {
        float4 f = a4[v];
        av[4*v] = f.x; av[4*v+1] = f.y; av[4*v+2] = f.z; av[4*v+3] = f.w;
    }
#pragma unroll
    for (int c = 0; c < CPG; ++c) m[c] = -INFINITY;

    const int4* kn = (const int4*)(knn + (size_t)i * 16);
#pragma unroll
    for (int kk = 0; kk < 4; ++kk) {
        int4 n4 = kn[kk];
        int js[4] = { n4.x, n4.y, n4.z, n4.w };
#pragma unroll
        for (int u = 0; u < 4; ++u) {
            const float4* c4 = (const float4*)(cf + (size_t)js[u] * COUT + g * CPG);
#pragma unroll
            for (int v = 0; v < CPG / 4; ++v) {
                float4 f = c4[v];
                m[4*v+0] = fmaxf(m[4*v+0], av[4*v+0] + f.x);
                m[4*v+1] = fmaxf(m[4*v+1], av[4*v+1] + f.y);
                m[4*v+2] = fmaxf(m[4*v+2], av[4*v+2] + f.z);
                m[4*v+3] = fmaxf(m[4*v+3], av[4*v+3] + f.w);
            }
        }
    }
    float xv[CPG];
#pragma unroll
    for (int c = 0; c < CPG; ++c) xv[c] = fmaxf(m[c], 0.0f);

    if constexpr (LAST) {
        float4* o4 = (float4*)(out + (size_t)i * COUT + g * CPG);
#pragma unroll
        for (int v = 0; v < CPG / 4; ++v)
            o4[v] = make_float4(xv[4*v], xv[4*v+1], xv[4*v+2], xv[4*v+3]);
    } else {
#pragma unroll
        for (int c = 0; c < CPG; ++c) xs[p][g * CPG + c] = xv[c];
        __syncthreads();

        float aacc[CPGN], cacc[CPGN];
        const float4* bn4 = (const float4*)(bn + g * CPGN);
#pragma unroll
        for (int v = 0; v < CPGN / 4; ++v) {
            float4 f = bn4[v];
            aacc[4*v] = f.x; aacc[4*v+1] = f.y; aacc[4*v+2] = f.z; aacc[4*v+3] = f.w;
        }
#pragma unroll
        for (int c = 0; c < CPGN; ++c) cacc[c] = 0.0f;

#pragma unroll
        for (int r = 0; r < COUT; ++r) {
            float xr = xs[p][r];
            const float4* wm4 = (const float4*)(wm + r * CNXT + g * CPGN);
            const float4* wb4 = (const float4*)(wb + r * CNXT + g * CPGN);
#pragma unroll
            for (int v = 0; v < CPGN / 4; ++v) {
                float4 fm = wm4[v], fb = wb4[v];
                aacc[4*v+0] = fmaf(xr, fm.x, aacc[4*v+0]);
                aacc[4*v+1] = fmaf(xr, fm.y, aacc[4*v+1]);
                aacc[4*v+2] = fmaf(xr, fm.z, aacc[4*v+2]);
                aacc[4*v+3] = fmaf(xr, fm.w, aacc[4*v+3]);
                cacc[4*v+0] = fmaf(xr, fb.x, cacc[4*v+0]);
                cacc[4*v+1] = fmaf(xr, fb.y, cacc[4*v+1]);
                cacc[4*v+2] = fmaf(xr, fb.z, cacc[4*v+2]);
                cacc[4*v+3] = fmaf(xr, fb.w, cacc[4*v+3]);
            }
        }
        float4* an4 = (float4*)(an + (size_t)i * CNXT + g * CPGN);
        float4* cn4 = (float4*)(cn + (size_t)i * CNXT + g * CPGN);
#pragma unroll
        for (int v = 0; v < CPGN / 4; ++v) {
            an4[v] = make_float4(aacc[4*v], aacc[4*v+1], aacc[4*v+2], aacc[4*v+3]);
            cn4[v] = make_float4(cacc[4*v], cacc[4*v+1], cacc[4*v+2], cacc[4*v+3]);
        }
    }
}

// ---------------------------------------------------------------------------
// Workspace layout (bytes), peak 34.2 MB (< 37 proven):
//   [0,24M)   : surv (32768 x 192 int, segmented 32x6)  -- dead after P3
//   [24M,32M) : pb2T (64 x 32768 float, transposed)     -- dead after tau
//     reuse (post-tau): knn [24,26) ; a1 [26,28) ; c1 [28,30)
//   [30M,34M) : pc  (32768 x 32 int)
//   [34M,+128K): tau
//   reuse (post-select): a2=[0,4M) c2=[4,8M) a3=[8,12M) c3=[12,16M)
// ---------------------------------------------------------------------------
extern "C" void kernel_launch(void* const* d_in, const int* in_sizes, int n_in,
                              void* d_out, int out_size, void* d_ws, size_t ws_size,
                              hipStream_t stream) {
    const float4* coords = (const float4*)d_in[0];
    const float*  feat   = (const float*)d_in[1];
    const float*  W1 = (const float*)d_in[2];
    const float*  b1 = (const float*)d_in[3];
    const float*  W2 = (const float*)d_in[4];
    const float*  b2 = (const float*)d_in[5];
    const float*  W3 = (const float*)d_in[6];
    const float*  b3 = (const float*)d_in[7];
    float* out = (float*)d_out;

    char* ws = (char*)d_ws;
    int*   surv = (int*)  (ws);
    float* pb2T = (float*)(ws + (24u << 20));
    int*   knn  = (int*)  (ws + (24u << 20));   // overlaps pb2T (dead after tau)
    float* a1   = (float*)(ws + (26u << 20));
    float* c1   = (float*)(ws + (28u << 20));
    int*   pc   = (int*)  (ws + (30u << 20));
    float* tau  = (float*)(ws + (34u << 20));
    float* a2   = (float*)(ws + (0u  << 20));
    float* c2   = (float*)(ws + (4u  << 20));
    float* a3   = (float*)(ws + (8u  << 20));
    float* c3   = (float*)(ws + (12u << 20));

    knn_bound_kernel<<<dim3(NPTS / QBLK, CSPLIT), 256, 0, stream>>>(coords, pb2T);
    tau_init_kernel<<<NPTS / 256, 256, 0, stream>>>(pb2T, tau);
    knn_filter_kernel<<<dim3(NPTS / QBLK, CSPLIT), 256, 0, stream>>>(coords, tau, pc, surv);
    knn_select_ac1_kernel<<<NPTS / SELQ, 256, 0, stream>>>(coords, pc, surv, feat, W1, b1, knn, a1, c1);
    edgeconv_kernel<16, 32, false><<<NPTS / 64, 256, 0, stream>>>(a1, c1, knn, W2, b2, a2, c2, nullptr);
    edgeconv_kernel<32, 32, false><<<NPTS / 64, 256, 0, stream>>>(a2, c2, knn, W3, b3, a3, c3, nullptr);
    edgeconv_kernel<32, 4, true><<<NPTS / 64, 256, 0, stream>>>(a3, c3, knn, nullptr, nullptr, nullptr, nullptr, out);
}